// Round 1
// baseline (95.595 us; speedup 1.0000x reference)
//
#include <hip/hip_runtime.h>

// Problem constants (fixed by setup_inputs): B=8, N=128, C=64(d), S=64, basis=20
constexpr int N = 128;
constexpr float INV_AVG = 1.0f / 49.0f;   // AVG_NOBJ
constexpr float SLOPE = 0.01f;            // leaky_relu neg slope
constexpr int XP = 68;                    // padded x-row stride (floats) -> bank-spread

// ---- LDS layout (float offsets), single block-private arena ~105 KB ----
constexpr int O_XS   = 0;                 // [128][XP]   staged x[n]
constexpr int O_W2   = O_XS + 128 * XP;   // [64][64]    w2[d][s] (sum over b=1,6,11,16)
constexpr int O_R    = O_W2 + 4096;       // [128][64]   R[j][s] = sum_d x[j,d] w2[d,s]
constexpr int O_PART = O_R + 8192;        // [10][8][64] reduction partials (reused)
constexpr int O_AG   = O_PART + 5120;     // [4][64]     {sum/49, sum/nobj, max, min}
constexpr int O_BV   = O_AG + 256;        // [4][64]     base = C + E + bias
constexpr int O_DV   = O_BV + 256;        // [4][64]     diag = A + D
constexpr int LDS_F  = O_DV + 256;        // 26880 floats = 105 KB

// ---------------------------------------------------------------------------
// ONE fused kernel, grid 256 (1 block/CU), 512 threads (8 waves/CU).
// Block b: n = b>>5, i0 = (b&31)*4. Each block redundantly recomputes its
// prep state (coefs pass is L2-hot, R-GEMM is 0.5M FMA ~ cheap) — this
// removes the kernel boundary + ws round-trip WITHOUT a cooperative
// grid.sync (R8 lesson: that barrier costs 100+ us on 8 XCDs).
//   out[n,i,j,s] = leaky(base[n,i,s] + R[n,j,s] + d_ij*diag[n,i,s]) * mask
// Stores are plain cached float4 (out = 32 MB = aggregate L2; dirty lines
// may drain after kernel end) — replaces the previous nontemporal path.
// ---------------------------------------------------------------------------
__global__ __launch_bounds__(512, 1) void fused_kernel(
    const float* __restrict__ x,      // [8][128][64]
    const float* __restrict__ mask,   // [8][128][128][1]
    const float* __restrict__ nobj,   // [8]
    const float* __restrict__ coefs,  // [64][64][20]
    const float* __restrict__ bias,   // [64]
    float* __restrict__ out)          // [8][128][128][64]
{
  __shared__ __align__(16) float lds[LDS_F];
  float* xs    = lds + O_XS;
  float* w2s   = lds + O_W2;
  float* Rr    = lds + O_R;
  float* part  = lds + O_PART;
  float* ag    = lds + O_AG;
  float* basev = lds + O_BV;
  float* diagv = lds + O_DV;

  const int tid = threadIdx.x;
  const int n   = blockIdx.x >> 5;
  const int i0  = (blockIdx.x & 31) << 2;

  // ---- P0: stage x[n] (32 KB, coalesced float4, padded rows) ----
  {
    const float4* xg = (const float4*)(x + (size_t)n * N * 64);
#pragma unroll
    for (int q = 0; q < 4; ++q) {
      const int idx = q * 512 + tid;        // 0..2047 f4
      const int j = idx >> 4, c = idx & 15;
      *(float4*)(xs + j * XP + c * 4) = xg[idx];
    }
  }
  __syncthreads();

  // ---- P1: aggregations over i (sum/max/min per d) ----
  {
    const int d = tid & 63, grp = tid >> 6;     // 8 groups x 16 rows
    float sm = 0.f, mx = -INFINITY, mn = INFINITY;
    for (int i = grp * 16; i < grp * 16 + 16; ++i) {
      float v = xs[i * XP + d];
      sm += v; mx = fmaxf(mx, v); mn = fminf(mn, v);
    }
    part[grp * 64 + d]        = sm;
    part[512 + grp * 64 + d]  = mx;
    part[1024 + grp * 64 + d] = mn;
  }
  __syncthreads();
  if (tid < 64) {
    float s0 = 0.f, m0 = -INFINITY, n0 = INFINITY;
#pragma unroll
    for (int g = 0; g < 8; ++g) {
      s0 += part[g * 64 + tid];
      m0 = fmaxf(m0, part[512 + g * 64 + tid]);
      n0 = fminf(n0, part[1024 + g * 64 + tid]);
    }
    ag[tid]       = s0 * INV_AVG;   // 'sum'
    ag[64 + tid]  = s0 / nobj[n];   // 'mean'
    ag[128 + tid] = m0;             // 'max'
    ag[192 + tid] = n0;             // 'min'
  }
  __syncthreads();

  // ---- P2: single coefs pass. e = d*64+s covered once; fold w1/w3/D/E for
  //          this block's 4 rows, materialize w2[d][s] for the R-GEMM. ----
  {
    const int g = tid >> 6;                 // 0..7
    const int s = tid & 63;
    float pA[4] = {0,0,0,0}, pC[4] = {0,0,0,0};
    float pD = 0.f, pE = 0.f;
#pragma unroll
    for (int k = 0; k < 8; ++k) {
      const int e = k * 512 + tid;          // e = d*64 + s
      const int d = k * 8 + g;              // wave-uniform
      const float4* cp = (const float4*)(coefs + (size_t)e * 20);  // 80 B rows
      float4 f0 = cp[0], f1 = cp[1], f2 = cp[2], f3 = cp[3], f4v = cp[4];
      float w1v = f0.x + f1.y + f2.z + f3.w;     // b = 0,5,10,15  (diag x_i)
      float w2v = f0.y + f1.z + f2.w + f4v.x;    // b = 1,6,11,16  (row x_j)
      float w3v = f0.z + f1.w + f3.x + f4v.y;    // b = 2,7,12,17  (col x_i)
      w2s[e] = w2v;
#pragma unroll
      for (int m = 0; m < 4; ++m) {
        float xv = xs[(i0 + m) * XP + d];        // wave-uniform broadcast
        pA[m] += xv * w1v;
        pC[m] += xv * w3v;
      }
      pD += ag[d] * f0.w + ag[64 + d] * f2.x + ag[128 + d] * f3.y + ag[192 + d] * f4v.z;
      pE += ag[d] * f1.x + ag[64 + d] * f2.y + ag[128 + d] * f3.z + ag[192 + d] * f4v.w;
    }
#pragma unroll
    for (int m = 0; m < 4; ++m) {
      part[m * 512 + g * 64 + s]       = pA[m];
      part[(4 + m) * 512 + g * 64 + s] = pC[m];
    }
    part[8 * 512 + g * 64 + s] = pD;
    part[9 * 512 + g * 64 + s] = pE;
  }
  __syncthreads();

  // ---- P4: R-GEMM in LDS. R[j][s] = sum_d xs[j][d] * w2[d][s].
  //          thread: s4 = tid&15 (f4 over s), 4 consecutive j. ----
  {
    const int s4 = tid & 15;
    const int j0 = (tid >> 4) * 4;          // 0..124
    const float4* w2q = (const float4*)w2s; // index d*16 + s4
    float4 acc[4];
#pragma unroll
    for (int jj = 0; jj < 4; ++jj) { acc[jj].x = acc[jj].y = acc[jj].z = acc[jj].w = 0.f; }
#pragma unroll
    for (int d0 = 0; d0 < 16; ++d0) {
      float4 w0 = w2q[(d0 * 4 + 0) * 16 + s4];
      float4 w1 = w2q[(d0 * 4 + 1) * 16 + s4];
      float4 w2 = w2q[(d0 * 4 + 2) * 16 + s4];
      float4 w3 = w2q[(d0 * 4 + 3) * 16 + s4];
#pragma unroll
      for (int jj = 0; jj < 4; ++jj) {
        float4 xv = *(const float4*)(xs + (j0 + jj) * XP + d0 * 4);  // broadcast, pad=68 avoids conflicts
        acc[jj].x += xv.x * w0.x + xv.y * w1.x + xv.z * w2.x + xv.w * w3.x;
        acc[jj].y += xv.x * w0.y + xv.y * w1.y + xv.z * w2.y + xv.w * w3.y;
        acc[jj].z += xv.x * w0.z + xv.y * w1.z + xv.z * w2.z + xv.w * w3.z;
        acc[jj].w += xv.x * w0.w + xv.y * w1.w + xv.z * w2.w + xv.w * w3.w;
      }
    }
#pragma unroll
    for (int jj = 0; jj < 4; ++jj)
      ((float4*)Rr)[(j0 + jj) * 16 + s4] = acc[jj];
  }

  // ---- P3: reduce partials -> base/diag for the 4 rows (256 threads) ----
  if (tid < 256) {
    const int m = tid >> 6, s = tid & 63;
    float A = 0.f, C = 0.f, D = 0.f, E = 0.f;
#pragma unroll
    for (int g = 0; g < 8; ++g) {
      A += part[m * 512 + g * 64 + s];
      C += part[(4 + m) * 512 + g * 64 + s];
      D += part[8 * 512 + g * 64 + s];
      E += part[9 * 512 + g * 64 + s];
    }
    basev[m * 64 + s] = C + E + bias[s];
    diagv[m * 64 + s] = A + D;
  }
  __syncthreads();

  // ---- P5: stream the 4x128x64 output tile (128 KB), coalesced f4 ----
  {
    const float* mrow = mask + (size_t)(n * N + i0) * N;
    float4* outq = (float4*)out + (size_t)(n * N + i0) * N * 16;
    const float4* Rq = (const float4*)Rr;
    const float4* bq = (const float4*)basev;
    const float4* dq = (const float4*)diagv;
#pragma unroll
    for (int q = 0; q < 16; ++q) {
      const int idx = q * 512 + tid;        // 0..8191 f4
      const int l = idx & 15;
      const int j = (idx >> 4) & 127;
      const int m = idx >> 11;
      float4 b = bq[m * 16 + l];
      float4 r = Rq[j * 16 + l];
      float mk = mrow[m * N + j];
      float v0 = b.x + r.x, v1 = b.y + r.y, v2 = b.z + r.z, v3 = b.w + r.w;
      if (i0 + m == j) {
        float4 dgv = dq[m * 16 + l];
        v0 += dgv.x; v1 += dgv.y; v2 += dgv.z; v3 += dgv.w;
      }
      v0 = (v0 >= 0.f) ? v0 : SLOPE * v0;
      v1 = (v1 >= 0.f) ? v1 : SLOPE * v1;
      v2 = (v2 >= 0.f) ? v2 : SLOPE * v2;
      v3 = (v3 >= 0.f) ? v3 : SLOPE * v3;
      float4 o;
      o.x = v0 * mk; o.y = v1 * mk; o.z = v2 * mk; o.w = v3 * mk;
      outq[idx] = o;                        // plain cached store (no NT)
    }
  }
}

extern "C" void kernel_launch(void* const* d_in, const int* in_sizes, int n_in,
                              void* d_out, int out_size, void* d_ws, size_t ws_size,
                              hipStream_t stream) {
  const float* x     = (const float*)d_in[0];   // [8][128][64]
  const float* mask  = (const float*)d_in[1];   // [8][128][128][1]
  const float* nobj  = (const float*)d_in[2];   // [8]
  const float* coefs = (const float*)d_in[3];   // [64][64][20]
  const float* bias  = (const float*)d_in[4];   // [64]
  float* out = (float*)d_out;                   // [8][128][128][64]

  fused_kernel<<<256, 512, 0, stream>>>(x, mask, nobj, coefs, bias, out);
}

// Round 2
// 89.358 us; speedup vs baseline: 1.0698x; 1.0698x over previous
//
#include <hip/hip_runtime.h>

// Problem constants (fixed by setup_inputs): B=8, N=128, C=64(d), S=64, basis=20
constexpr int N = 128;
constexpr float INV_AVG = 1.0f / 49.0f;   // AVG_NOBJ
constexpr float SLOPE = 0.01f;            // leaky_relu neg slope
constexpr int XP = 68;                    // padded x-row stride (floats) -> bank-spread

typedef float f4 __attribute__((ext_vector_type(4)));

// ---- LDS layout (float offsets), single block-private arena = 128 KB ----
constexpr int O_XS   = 0;                  // [128][XP]    staged x[n] (8704)
constexpr int O_W2   = O_XS + 128 * XP;    // [64][64]     w2[d][s]    (4096)
constexpr int O_R    = O_W2 + 4096;        // [128][64]    R[j][s]     (8192)
constexpr int O_PART = O_R + 8192;         // [10][16][64] partials    (10240)
constexpr int O_AG   = O_PART + 10240;     // [4][64]      aggregates
constexpr int O_BV   = O_AG + 256;         // [4][64]      base = C+E+bias
constexpr int O_DV   = O_BV + 256;         // [4][64]      diag = A+D
constexpr int LDS_F  = O_DV + 256;         // 32000 floats = 128 KB

// ---------------------------------------------------------------------------
// ONE fused kernel, grid 256 (1 block/CU), 1024 threads (16 waves/CU).
// Block b: n = b>>5, i0 = (b&31)*4. Each block redundantly recomputes its
// prep state (coefs pass L2-hot, R-GEMM cheap) — removes the kernel boundary
// WITHOUT cooperative grid.sync (R8: that barrier costs 100+ us on 8 XCDs).
//   out[n,i,j,s] = leaky(base[n,i,s] + R[n,j,s] + d_ij*diag[n,i,s]) * mask
// R1 lesson: 512-thread fused version regressed — 8 waves/CU couldn't hide
// store latency AND cached stores left 32 MB dirty L2 that slowed the
// harness re-poison fills (6.14 -> 5.8 TB/s). Fix: 1024 threads + NT stores.
// ---------------------------------------------------------------------------
__global__ __launch_bounds__(1024, 1) void fused_kernel(
    const float* __restrict__ x,      // [8][128][64]
    const float* __restrict__ mask,   // [8][128][128][1]
    const float* __restrict__ nobj,   // [8]
    const float* __restrict__ coefs,  // [64][64][20]
    const float* __restrict__ bias,   // [64]
    float* __restrict__ out)          // [8][128][128][64]
{
  __shared__ __align__(16) float lds[LDS_F];
  float* xs    = lds + O_XS;
  float* w2s   = lds + O_W2;
  float* Rr    = lds + O_R;
  float* part  = lds + O_PART;
  float* ag    = lds + O_AG;
  float* basev = lds + O_BV;
  float* diagv = lds + O_DV;

  const int tid = threadIdx.x;
  const int n   = blockIdx.x >> 5;
  const int i0  = (blockIdx.x & 31) << 2;

  // ---- P0: stage x[n] (32 KB, coalesced float4, padded rows) ----
  {
    const float4* xg = (const float4*)(x + (size_t)n * N * 64);
#pragma unroll
    for (int q = 0; q < 2; ++q) {
      const int idx = q * 1024 + tid;       // 0..2047 f4
      const int j = idx >> 4, c = idx & 15;
      *(float4*)(xs + j * XP + c * 4) = xg[idx];
    }
  }
  __syncthreads();

  // ---- P1: aggregations over i (sum/max/min per d), 16 groups x 8 rows ----
  {
    const int d = tid & 63, grp = tid >> 6;     // grp 0..15
    float sm = 0.f, mx = -INFINITY, mn = INFINITY;
    for (int i = grp * 8; i < grp * 8 + 8; ++i) {
      float v = xs[i * XP + d];
      sm += v; mx = fmaxf(mx, v); mn = fminf(mn, v);
    }
    part[grp * 64 + d]        = sm;
    part[1024 + grp * 64 + d] = mx;
    part[2048 + grp * 64 + d] = mn;
  }
  __syncthreads();
  if (tid < 64) {
    float s0 = 0.f, m0 = -INFINITY, n0 = INFINITY;
#pragma unroll
    for (int g = 0; g < 16; ++g) {
      s0 += part[g * 64 + tid];
      m0 = fmaxf(m0, part[1024 + g * 64 + tid]);
      n0 = fminf(n0, part[2048 + g * 64 + tid]);
    }
    ag[tid]       = s0 * INV_AVG;   // 'sum'
    ag[64 + tid]  = s0 / nobj[n];   // 'mean'
    ag[128 + tid] = m0;             // 'max'
    ag[192 + tid] = n0;             // 'min'
  }
  __syncthreads();

  // ---- P2: single coefs pass (each e = d*64+s covered once; 4 iters) ----
  {
    const int g = tid >> 6;                 // 0..15
    const int s = tid & 63;
    float pA[4] = {0,0,0,0}, pC[4] = {0,0,0,0};
    float pD = 0.f, pE = 0.f;
#pragma unroll
    for (int k = 0; k < 4; ++k) {
      const int e = k * 1024 + tid;         // e = d*64 + s
      const int d = k * 16 + g;             // wave-uniform
      const float4* cp = (const float4*)(coefs + (size_t)e * 20);  // 80 B rows
      float4 f0 = cp[0], f1 = cp[1], f2 = cp[2], f3 = cp[3], f4v = cp[4];
      float w1v = f0.x + f1.y + f2.z + f3.w;     // b = 0,5,10,15  (diag x_i)
      float w2v = f0.y + f1.z + f2.w + f4v.x;    // b = 1,6,11,16  (row x_j)
      float w3v = f0.z + f1.w + f3.x + f4v.y;    // b = 2,7,12,17  (col x_i)
      w2s[e] = w2v;
#pragma unroll
      for (int m = 0; m < 4; ++m) {
        float xv = xs[(i0 + m) * XP + d];        // wave-uniform broadcast
        pA[m] += xv * w1v;
        pC[m] += xv * w3v;
      }
      pD += ag[d] * f0.w + ag[64 + d] * f2.x + ag[128 + d] * f3.y + ag[192 + d] * f4v.z;
      pE += ag[d] * f1.x + ag[64 + d] * f2.y + ag[128 + d] * f3.z + ag[192 + d] * f4v.w;
    }
#pragma unroll
    for (int m = 0; m < 4; ++m) {
      part[m * 1024 + g * 64 + s]       = pA[m];
      part[(4 + m) * 1024 + g * 64 + s] = pC[m];
    }
    part[8 * 1024 + g * 64 + s] = pD;
    part[9 * 1024 + g * 64 + s] = pE;
  }
  __syncthreads();

  // ---- P4: R-GEMM in LDS. R[j][s] = sum_d xs[j][d] * w2[d][s].
  //          thread: s4 = tid&15 (f4 over s), 2 consecutive j. ----
  {
    const int s4 = tid & 15;
    const int j0 = (tid >> 4) * 2;          // 0..126
    const float4* w2q = (const float4*)w2s; // index d*16 + s4
    float4 acc[2];
#pragma unroll
    for (int jj = 0; jj < 2; ++jj) { acc[jj].x = acc[jj].y = acc[jj].z = acc[jj].w = 0.f; }
#pragma unroll
    for (int d0 = 0; d0 < 16; ++d0) {
      float4 w0 = w2q[(d0 * 4 + 0) * 16 + s4];
      float4 w1 = w2q[(d0 * 4 + 1) * 16 + s4];
      float4 w2 = w2q[(d0 * 4 + 2) * 16 + s4];
      float4 w3 = w2q[(d0 * 4 + 3) * 16 + s4];
#pragma unroll
      for (int jj = 0; jj < 2; ++jj) {
        float4 xv = *(const float4*)(xs + (j0 + jj) * XP + d0 * 4);  // 4 bcast addrs, disjoint banks
        acc[jj].x += xv.x * w0.x + xv.y * w1.x + xv.z * w2.x + xv.w * w3.x;
        acc[jj].y += xv.x * w0.y + xv.y * w1.y + xv.z * w2.y + xv.w * w3.y;
        acc[jj].z += xv.x * w0.z + xv.y * w1.z + xv.z * w2.z + xv.w * w3.z;
        acc[jj].w += xv.x * w0.w + xv.y * w1.w + xv.z * w2.w + xv.w * w3.w;
      }
    }
#pragma unroll
    for (int jj = 0; jj < 2; ++jj)
      ((float4*)Rr)[(j0 + jj) * 16 + s4] = acc[jj];
  }

  // ---- P3: reduce partials -> base/diag for the 4 rows (256 threads) ----
  if (tid < 256) {
    const int m = tid >> 6, s = tid & 63;
    float A = 0.f, C = 0.f, D = 0.f, E = 0.f;
#pragma unroll
    for (int g = 0; g < 16; ++g) {
      A += part[m * 1024 + g * 64 + s];
      C += part[(4 + m) * 1024 + g * 64 + s];
      D += part[8 * 1024 + g * 64 + s];
      E += part[9 * 1024 + g * 64 + s];
    }
    basev[m * 64 + s] = C + E + bias[s];
    diagv[m * 64 + s] = A + D;
  }
  __syncthreads();

  // ---- P5: stream the 4x128x64 output tile (128 KB), NT coalesced f4 ----
  {
    const float* mrow = mask + (size_t)(n * N + i0) * N;
    f4* outq = (f4*)out + (size_t)(n * N + i0) * N * 16;
    const float4* Rq = (const float4*)Rr;
    const float4* bq = (const float4*)basev;
    const float4* dq = (const float4*)diagv;
#pragma unroll
    for (int q = 0; q < 8; ++q) {
      const int idx = q * 1024 + tid;       // 0..8191 f4
      const int l = idx & 15;
      const int j = (idx >> 4) & 127;
      const int m = idx >> 11;
      float4 b = bq[m * 16 + l];
      float4 r = Rq[j * 16 + l];
      float mk = mrow[m * N + j];
      float v0 = b.x + r.x, v1 = b.y + r.y, v2 = b.z + r.z, v3 = b.w + r.w;
      if (i0 + m == j) {
        float4 dgv = dq[m * 16 + l];
        v0 += dgv.x; v1 += dgv.y; v2 += dgv.z; v3 += dgv.w;
      }
      v0 = (v0 >= 0.f) ? v0 : SLOPE * v0;
      v1 = (v1 >= 0.f) ? v1 : SLOPE * v1;
      v2 = (v2 >= 0.f) ? v2 : SLOPE * v2;
      v3 = (v3 >= 0.f) ? v3 : SLOPE * v3;
      f4 o;
      o.x = v0 * mk; o.y = v1 * mk; o.z = v2 * mk; o.w = v3 * mk;
      __builtin_nontemporal_store(o, &outq[idx]);   // keep L2 clean for harness fills
    }
  }
}

extern "C" void kernel_launch(void* const* d_in, const int* in_sizes, int n_in,
                              void* d_out, int out_size, void* d_ws, size_t ws_size,
                              hipStream_t stream) {
  const float* x     = (const float*)d_in[0];   // [8][128][64]
  const float* mask  = (const float*)d_in[1];   // [8][128][128][1]
  const float* nobj  = (const float*)d_in[2];   // [8]
  const float* coefs = (const float*)d_in[3];   // [64][64][20]
  const float* bias  = (const float*)d_in[4];   // [64]
  float* out = (float*)d_out;                   // [8][128][128][64]

  fused_kernel<<<256, 1024, 0, stream>>>(x, mask, nobj, coefs, bias, out);
}

// Round 3
// 82.294 us; speedup vs baseline: 1.1616x; 1.0858x over previous
//
#include <hip/hip_runtime.h>

// Problem constants (fixed by setup_inputs): B=8, N=128, C=64, S=64, basis=20
constexpr int N = 128, S = 64;
constexpr float INV_AVG = 1.0f / 49.0f;   // AVG_NOBJ
constexpr float SLOPE = 0.01f;            // leaky_relu neg slope

typedef float f4 __attribute__((ext_vector_type(4)));

// Workspace layout (float offsets) — only 2.3 MB used
constexpr int WS_BASE = 0;        // [8][128][64]  Cc + E + bias  (j-invariant)
constexpr int WS_DIAG = 65536;    // [8][128][64]  A + D          (diagonal)
constexpr int WS_R    = 131072;   // [8][128][64]  x·W2           (row term)

// ---------------------------------------------------------------------------
// Kernel 1 (grid 256, 512 thr): block = (n, 4 i-rows). One streamed coefs
// pass (L2-hot) computes A,R,Cc per row + redundant agg/D/E; writes
// pre-folded base/diag/R.
//   out[n,i,j,s] = leaky( base[n,i,s] + R[n,j,s] + d_ij*diag[n,i,s] ) * mask
// R1/R2 lesson: do NOT fuse with assemble — fused single-dispatch measured
// 89-96 us vs 84 for this structure (prologue serializes ahead of the 32 MB
// stream with too few store waves). R8 lesson: no cooperative grid.sync
// (100+ us on 8 XCDs). This round: 512 threads (was 256) halves the coefs
// loop depth; the fold/write phase uses 256 threads in one shot.
// ---------------------------------------------------------------------------
__global__ __launch_bounds__(512) void prep_kernel(
    const float* __restrict__ x,      // [8][128][64]
    const float* __restrict__ nobj,   // [8]
    const float* __restrict__ coefs,  // [64][64][20]
    const float* __restrict__ bias,   // [64]
    float* __restrict__ ws)
{
  __shared__ float xs[8192];     // x[n] [i][d]
  __shared__ float ag[256];      // [4][64] {sum/49, sum/nobj, max, min}
  __shared__ float part[7168];   // P1: 3x512 partials; P2: 14x512 partials

  const int tid = threadIdx.x;
  const int n   = blockIdx.x >> 5;
  const int i0  = (blockIdx.x & 31) << 2;

  // ---- P0: stage x[n] (32 KB, coalesced float4) ----
  {
    const float4* xg = (const float4*)(x + n * N * 64);
    float4* xs4 = (float4*)xs;
#pragma unroll
    for (int k = 0; k < 4; ++k) xs4[tid + k * 512] = xg[tid + k * 512];
  }
  __syncthreads();

  // ---- P1: aggregations over i (sum/max/min), 8 groups x 16 rows ----
  {
    const int d = tid & 63, grp = tid >> 6;
    float sm = 0.f, mx = -INFINITY, mn = INFINITY;
    for (int i = grp * 16; i < grp * 16 + 16; ++i) {
      float v = xs[i * 64 + d];          // 2-way bank (free)
      sm += v; mx = fmaxf(mx, v); mn = fminf(mn, v);
    }
    part[grp * 64 + d]        = sm;
    part[512 + grp * 64 + d]  = mx;
    part[1024 + grp * 64 + d] = mn;
  }
  __syncthreads();
  if (tid < 64) {
    float s0 = 0.f, m0 = -INFINITY, n0 = INFINITY;
#pragma unroll
    for (int g = 0; g < 8; ++g) {
      s0 += part[g * 64 + tid];
      m0 = fmaxf(m0, part[512 + g * 64 + tid]);
      n0 = fminf(n0, part[1024 + g * 64 + tid]);
    }
    ag[tid]       = s0 * INV_AVG;   // 'sum'
    ag[64 + tid]  = s0 / nobj[n];   // 'mean'
    ag[128 + tid] = m0;             // 'max'
    ag[192 + tid] = n0;             // 'min'
  }
  __syncthreads();

  // ---- P2: one coefs pass. Thread covers s=tid&63, d = k*8+(tid>>6). ----
  {
    const int g = tid >> 6;                 // 0..7
    const int s = tid & 63;
    float pA[4] = {0,0,0,0}, pR[4] = {0,0,0,0}, pC[4] = {0,0,0,0};
    float pD = 0.f, pE = 0.f;
#pragma unroll
    for (int k = 0; k < 8; ++k) {
      const int e = k * 512 + tid;               // e = d*64 + s
      const int d = k * 8 + g;                   // wave-uniform
      const float4* cp = (const float4*)(coefs + (size_t)e * 20);  // 80B rows
      float4 f0 = cp[0], f1 = cp[1], f2 = cp[2], f3 = cp[3], f4v = cp[4];
      float w1v = f0.x + f1.y + f2.z + f3.w;     // b = 0,5,10,15
      float w2v = f0.y + f1.z + f2.w + f4v.x;    // b = 1,6,11,16
      float w3v = f0.z + f1.w + f3.x + f4v.y;    // b = 2,7,12,17
#pragma unroll
      for (int m = 0; m < 4; ++m) {
        float xv = xs[(i0 + m) * 64 + d];        // wave-uniform broadcast
        pA[m] += xv * w1v;
        pR[m] += xv * w2v;
        pC[m] += xv * w3v;
      }
      // D: cols 3,8,13,18 ; E: cols 4,9,14,19
      pD += ag[d] * f0.w + ag[64 + d] * f2.x + ag[128 + d] * f3.y + ag[192 + d] * f4v.z;
      pE += ag[d] * f1.x + ag[64 + d] * f2.y + ag[128 + d] * f3.z + ag[192 + d] * f4v.w;
    }
#pragma unroll
    for (int m = 0; m < 4; ++m) {
      part[m * 512 + g * 64 + s]        = pA[m];
      part[(4 + m) * 512 + g * 64 + s]  = pC[m];
      part[(8 + m) * 512 + g * 64 + s]  = pR[m];
    }
    part[12 * 512 + g * 64 + s] = pD;
    part[13 * 512 + g * 64 + s] = pE;
  }
  __syncthreads();

  // ---- P3: reduce + fold + write (256 threads, one shot, coalesced) ----
  if (tid < 256) {
    const int m = tid >> 6, s = tid & 63;
    float A = 0.f, C = 0.f, R = 0.f, D = 0.f, E = 0.f;
#pragma unroll
    for (int g = 0; g < 8; ++g) {
      A += part[m * 512 + g * 64 + s];
      C += part[(4 + m) * 512 + g * 64 + s];
      R += part[(8 + m) * 512 + g * 64 + s];
      D += part[12 * 512 + g * 64 + s];
      E += part[13 * 512 + g * 64 + s];
    }
    const int o = (n * N + i0 + m) * 64 + s;
    ws[WS_BASE + o] = C + E + bias[s];
    ws[WS_DIAG + o] = A + D;
    ws[WS_R    + o] = R;
  }
}

// ---------------------------------------------------------------------------
// Kernel 2 (grid 8192, deep occupancy): 1 float4 out per thread.
// 2 L2-hot loads + mask + rare diag; nontemporal coalesced float4 store
// (out is write-once -> skip L2 write-allocate, keep L2 for ws/mask).
// ---------------------------------------------------------------------------
__global__ __launch_bounds__(256) void assemble_kernel(
    const float* __restrict__ ws,
    const float* __restrict__ mask,   // [8][128][128][1]
    float* __restrict__ out)          // [8][128][128][64]
{
  const int g  = blockIdx.x * 256 + threadIdx.x;  // float4 index
  const int l  = g & 15;
  const int p  = g >> 4;         // (n*128+i)*128 + j
  const int j  = p & 127;
  const int bi = p >> 7;         // n*128 + i
  const int i  = bi & 127;
  const int n  = bi >> 7;

  const float4* B4 = (const float4*)(ws + WS_BASE);
  const float4* G4 = (const float4*)(ws + WS_DIAG);
  const float4* R4 = (const float4*)(ws + WS_R);

  float4 b = B4[bi * 16 + l];
  float4 r = R4[(n * N + j) * 16 + l];
  float mk = mask[p];

  float v0 = b.x + r.x;
  float v1 = b.y + r.y;
  float v2 = b.z + r.z;
  float v3 = b.w + r.w;
  if (i == j) {
    float4 dg = G4[bi * 16 + l];
    v0 += dg.x; v1 += dg.y; v2 += dg.z; v3 += dg.w;
  }
  v0 = (v0 >= 0.f) ? v0 : SLOPE * v0;
  v1 = (v1 >= 0.f) ? v1 : SLOPE * v1;
  v2 = (v2 >= 0.f) ? v2 : SLOPE * v2;
  v3 = (v3 >= 0.f) ? v3 : SLOPE * v3;

  f4 o;
  o.x = v0 * mk; o.y = v1 * mk; o.z = v2 * mk; o.w = v3 * mk;
  __builtin_nontemporal_store(o, &((f4*)out)[g]);
}

extern "C" void kernel_launch(void* const* d_in, const int* in_sizes, int n_in,
                              void* d_out, int out_size, void* d_ws, size_t ws_size,
                              hipStream_t stream) {
  const float* x     = (const float*)d_in[0];   // [8][128][64]
  const float* mask  = (const float*)d_in[1];   // [8][128][128][1]
  const float* nobj  = (const float*)d_in[2];   // [8]
  const float* coefs = (const float*)d_in[3];   // [64][64][20]
  const float* bias  = (const float*)d_in[4];   // [64]
  float* out = (float*)d_out;                   // [8][128][128][64]
  float* ws  = (float*)d_ws;                    // 196608 floats (~786 KB)

  prep_kernel<<<256, 512, 0, stream>>>(x, nobj, coefs, bias, ws);
  assemble_kernel<<<8192, 256, 0, stream>>>(ws, mask, out);
}